// Round 1
// baseline (178.342 us; speedup 1.0000x reference)
//
#include <hip/hip_runtime.h>
#include <math.h>

#define NN 768
#define FF 128
#define VV 64
#define RH 16
#define CHUNK 256

__device__ __forceinline__ float silu_f(float a) {
  return a / (1.0f + __expf(-a));
}

// ---------------------------------------------------------------------------
// init: hs[n] = embed row; hsv[n] = embed @ Wsv[0]; hv = 0
// ---------------------------------------------------------------------------
__global__ __launch_bounds__(192) void init_kernel(
    const float* __restrict__ embed, const float* __restrict__ Wsv0,
    float* __restrict__ hs, float* __restrict__ hsv, float* __restrict__ hv)
{
  const int n = blockIdx.x, t = threadIdx.x;
  hv[n * 192 + t] = 0.0f;
  if (t < FF) hs[n * FF + t] = embed[t];
  if (t < VV) {
    float acc = 0.f;
    #pragma unroll 8
    for (int f = 0; f < FF; ++f) acc += embed[f] * Wsv0[f * VV + t];
    hsv[n * VV + t] = acc;
  }
}

// ---------------------------------------------------------------------------
// edge kernel: one block per receiver r. Computes
//   agg_s[r,f] = (1/64) * sum_s hs[s,f]   * dot(rf[s,r], Wr2s[:,f])
//   agg_v[r,v,d]=(1/64) * sum_s hsv[s,v]  * dot(rf[s,r], Wr2v[:,v]) * u[s,r,d]
// Self edge s==r contributes exactly 0 (d=0 -> rf=0, u=0) so we loop densely.
// waves 0,2: scalar path (lane owns features 2l,2l+1)
// waves 1,3: vector path (lane owns channel l)
// ---------------------------------------------------------------------------
__global__ __launch_bounds__(256) void edge_kernel(
    const float* __restrict__ x,
    const float* __restrict__ hs,
    const float* __restrict__ hsv,
    const float* __restrict__ Wr1,   // [16]      (layer slice)
    const float* __restrict__ Wr2s,  // [16][128]
    const float* __restrict__ Wr2v,  // [16][64]
    float* __restrict__ agg_s,       // [N][128]
    float* __restrict__ agg_v)       // [N][64][3]
{
  __shared__ float x_s[NN * 3];
  __shared__ float rf_s[CHUNK * RH];
  __shared__ float u_s[CHUNK * 4];

  const int r    = blockIdx.x;
  const int tid  = threadIdx.x;
  const int wid  = tid >> 6;
  const int lane = tid & 63;
  const bool is_scalar = ((wid & 1) == 0);

  for (int i = tid; i < NN * 3; i += 256) x_s[i] = x[i];

  float wr1[RH];
  #pragma unroll
  for (int h = 0; h < RH; ++h) wr1[h] = Wr1[h];

  float2 w2s[RH];
  float  w2v[RH];
  float acc0 = 0.f, acc1 = 0.f;
  float av0 = 0.f, av1 = 0.f, av2 = 0.f;
  if (is_scalar) {
    #pragma unroll
    for (int h = 0; h < RH; ++h)
      w2s[h] = *(const float2*)&Wr2s[h * FF + 2 * lane];
  } else {
    #pragma unroll
    for (int h = 0; h < RH; ++h)
      w2v[h] = Wr2v[h * VV + lane];
  }

  const float xr0 = x[r * 3 + 0], xr1 = x[r * 3 + 1], xr2 = x[r * 3 + 2];
  __syncthreads();

  for (int cb = 0; cb < NN; cb += CHUNK) {
    // ---- phase 1: thread tid handles sender cb+tid ----
    {
      const int s = cb + tid;
      const float vx = x_s[s * 3 + 0] - xr0;
      const float vy = x_s[s * 3 + 1] - xr1;
      const float vz = x_s[s * 3 + 2] - xr2;
      const float d  = sqrtf(vx * vx + vy * vy + vz * vz);
      const float iv = 1.0f / (d + 1e-8f);
      *(float4*)&u_s[tid * 4] = make_float4(vx * iv, vy * iv, vz * iv, 0.f);
      #pragma unroll
      for (int h = 0; h < RH; h += 4) {
        float4 rv;
        rv.x = silu_f(d * wr1[h + 0]);
        rv.y = silu_f(d * wr1[h + 1]);
        rv.z = silu_f(d * wr1[h + 2]);
        rv.w = silu_f(d * wr1[h + 3]);
        *(float4*)&rf_s[tid * RH + h] = rv;
      }
    }
    __syncthreads();

    // ---- phase 2 ----
    const int base = (wid >> 1) * 128;  // which half of the chunk this wave owns
    if (is_scalar) {
      const float* hsp = hs + (size_t)cb * FF + 2 * lane;
      #pragma unroll 2
      for (int si = 0; si < 128; ++si) {
        const int sl = base + si;
        const float4* rp = (const float4*)&rf_s[sl * RH];
        float qv[RH];
        *(float4*)&qv[0]  = rp[0];
        *(float4*)&qv[4]  = rp[1];
        *(float4*)&qv[8]  = rp[2];
        *(float4*)&qv[12] = rp[3];
        const float2 h2 = *(const float2*)&hsp[(size_t)sl * FF];
        float ws0 = 0.f, ws1 = 0.f;
        #pragma unroll
        for (int h = 0; h < RH; ++h) {
          ws0 += qv[h] * w2s[h].x;
          ws1 += qv[h] * w2s[h].y;
        }
        acc0 += h2.x * ws0;
        acc1 += h2.y * ws1;
      }
    } else {
      const float* hvp = hsv + (size_t)cb * VV + lane;
      #pragma unroll 2
      for (int si = 0; si < 128; ++si) {
        const int sl = base + si;
        const float4* rp = (const float4*)&rf_s[sl * RH];
        float qv[RH];
        *(float4*)&qv[0]  = rp[0];
        *(float4*)&qv[4]  = rp[1];
        *(float4*)&qv[8]  = rp[2];
        *(float4*)&qv[12] = rp[3];
        const float hm = hvp[(size_t)sl * VV];
        float wv = 0.f;
        #pragma unroll
        for (int h = 0; h < RH; ++h) wv += qv[h] * w2v[h];
        const float m = hm * wv;
        const float4 u = *(const float4*)&u_s[sl * 4];
        av0 += m * u.x;
        av1 += m * u.y;
        av2 += m * u.z;
      }
    }
    __syncthreads();
  }

  // ---- cross-wave reduction (reuse rf_s as scratch) ----
  if (wid == 2) { rf_s[lane * 2] = acc0; rf_s[lane * 2 + 1] = acc1; }
  if (wid == 3) {
    rf_s[256 + lane * 3 + 0] = av0;
    rf_s[256 + lane * 3 + 1] = av1;
    rf_s[256 + lane * 3 + 2] = av2;
  }
  __syncthreads();
  if (wid == 0) {
    const float o0 = (acc0 + rf_s[lane * 2])     * (1.0f / 64.0f);
    const float o1 = (acc1 + rf_s[lane * 2 + 1]) * (1.0f / 64.0f);
    *(float2*)&agg_s[(size_t)r * FF + 2 * lane] = make_float2(o0, o1);
  }
  if (wid == 1) {
    agg_v[r * 192 + lane * 3 + 0] = (av0 + rf_s[256 + lane * 3 + 0]) * (1.0f / 64.0f);
    agg_v[r * 192 + lane * 3 + 1] = (av1 + rf_s[256 + lane * 3 + 1]) * (1.0f / 64.0f);
    agg_v[r * 192 + lane * 3 + 2] = (av2 + rf_s[256 + lane * 3 + 2]) * (1.0f / 64.0f);
  }
}

// ---------------------------------------------------------------------------
// node update: hs = silu(hs + agg_s@Wss + inv@Wvs); hv += agg_v@Wvv;
//              hsv = hs_new @ Wsv_next (for next layer)
// ---------------------------------------------------------------------------
__global__ __launch_bounds__(192) void node_kernel(
    const float* __restrict__ agg_s,    // [N][128]
    const float* __restrict__ agg_v,    // [N][192]
    const float* __restrict__ Wss,      // [128][128]
    const float* __restrict__ Wvs,      // [64][128]
    const float* __restrict__ Wvv,      // [64][64]
    const float* __restrict__ Wsv_next, // [128][64]
    float* __restrict__ hs,             // in/out [N][128]
    float* __restrict__ hsv,            // out [N][64]
    float* __restrict__ hv,             // in/out [N][192]
    int has_next)
{
  __shared__ float as_l[FF];
  __shared__ float av_l[192];
  __shared__ float inv_l[VV];
  __shared__ float hsn[FF];
  const int n = blockIdx.x, t = threadIdx.x;
  if (t < FF) as_l[t] = agg_s[n * FF + t];
  av_l[t] = agg_v[n * 192 + t];
  __syncthreads();
  if (t < VV) {
    const float a0 = av_l[t * 3 + 0], a1 = av_l[t * 3 + 1], a2 = av_l[t * 3 + 2];
    inv_l[t] = a0 * a0 + a1 * a1 + a2 * a2;
  }
  __syncthreads();
  if (t < FF) {
    float acc = hs[n * FF + t];
    #pragma unroll 4
    for (int k = 0; k < FF; ++k) acc += as_l[k] * Wss[k * FF + t];
    #pragma unroll 4
    for (int v = 0; v < VV; ++v) acc += inv_l[v] * Wvs[v * FF + t];
    const float hnew = silu_f(acc);
    hs[n * FF + t] = hnew;
    hsn[t] = hnew;
  }
  {
    const int w = t / 3, d = t - w * 3;  // t = w*3+d, t < 192
    float acc = hv[n * 192 + t];
    #pragma unroll 4
    for (int v = 0; v < VV; ++v) acc += av_l[v * 3 + d] * Wvv[v * VV + w];
    hv[n * 192 + t] = acc;
  }
  __syncthreads();
  if (has_next && t < VV) {
    float acc = 0.f;
    #pragma unroll 4
    for (int f = 0; f < FF; ++f) acc += hsn[f] * Wsv_next[f * VV + t];
    hsv[n * VV + t] = acc;
  }
}

// ---------------------------------------------------------------------------
// readout: out[n] = concat( silu(hs@Wro_s1)@Wro_s2 , ((hv@Wro_v1)@Wro_v2).flat )
// ---------------------------------------------------------------------------
__global__ __launch_bounds__(192) void readout_kernel(
    const float* __restrict__ hs,     // [N][128]
    const float* __restrict__ hv,     // [N][192]
    const float* __restrict__ Wro_s1, // [128][128]
    const float* __restrict__ Wro_s2, // [128][64]
    const float* __restrict__ Wro_v1, // [64][64]
    const float* __restrict__ Wro_v2, // [64][32]
    float* __restrict__ out)          // [N][160]
{
  __shared__ float hs_l[FF];
  __shared__ float hv_l[192];
  __shared__ float t1[FF];
  __shared__ float tv1[192];
  const int n = blockIdx.x, t = threadIdx.x;
  if (t < FF) hs_l[t] = hs[n * FF + t];
  hv_l[t] = hv[n * 192 + t];
  __syncthreads();
  if (t < FF) {
    float acc = 0.f;
    #pragma unroll 4
    for (int k = 0; k < FF; ++k) acc += hs_l[k] * Wro_s1[k * FF + t];
    t1[t] = silu_f(acc);
  }
  {
    const int w = t / 3, d = t - w * 3;  // t < 192
    float acc = 0.f;
    #pragma unroll 4
    for (int v = 0; v < VV; ++v) acc += hv_l[v * 3 + d] * Wro_v1[v * VV + w];
    tv1[t] = acc;
  }
  __syncthreads();
  if (t < 64) {
    float acc = 0.f;
    #pragma unroll 4
    for (int f = 0; f < FF; ++f) acc += t1[f] * Wro_s2[f * 64 + t];
    out[n * 160 + t] = acc;
  }
  if (t >= 64 && t < 160) {
    const int j = t - 64;
    const int w2 = j / 3, d = j - w2 * 3;
    float acc = 0.f;
    #pragma unroll 4
    for (int w = 0; w < VV; ++w) acc += tv1[w * 3 + d] * Wro_v2[w * 32 + w2];
    out[n * 160 + 64 + j] = acc;
  }
}

// ---------------------------------------------------------------------------
extern "C" void kernel_launch(void* const* d_in, const int* in_sizes, int n_in,
                              void* d_out, int out_size, void* d_ws, size_t ws_size,
                              hipStream_t stream) {
  const float* x      = (const float*)d_in[0];
  // d_in[1], d_in[2]: senders/receivers — unused (dense graph, diagonal is a no-op)
  const float* embed  = (const float*)d_in[3];
  const float* Wr1    = (const float*)d_in[4];   // [2][1][16]
  const float* Wr2s   = (const float*)d_in[5];   // [2][16][128]
  const float* Wr2v   = (const float*)d_in[6];   // [2][16][64]
  const float* Wsv    = (const float*)d_in[7];   // [2][128][64]
  const float* Wss    = (const float*)d_in[8];   // [2][128][128]
  const float* Wvs    = (const float*)d_in[9];   // [2][64][128]
  const float* Wvv    = (const float*)d_in[10];  // [2][64][64]
  const float* Wro_s1 = (const float*)d_in[11];
  const float* Wro_s2 = (const float*)d_in[12];
  const float* Wro_v1 = (const float*)d_in[13];
  const float* Wro_v2 = (const float*)d_in[14];

  float* ws_f = (float*)d_ws;
  float* hs   = ws_f;                 // [768][128]
  float* hsv  = hs   + NN * FF;       // [768][64]
  float* hv   = hsv  + NN * VV;       // [768][192]
  float* aggs = hv   + NN * 192;      // [768][128]
  float* aggv = aggs + NN * FF;       // [768][192]
  float* out  = (float*)d_out;

  init_kernel<<<NN, 192, 0, stream>>>(embed, Wsv, hs, hsv, hv);
  for (int l = 0; l < 2; ++l) {
    edge_kernel<<<NN, 256, 0, stream>>>(
        x, hs, hsv, Wr1 + l * RH, Wr2s + l * RH * FF, Wr2v + l * RH * VV,
        aggs, aggv);
    node_kernel<<<NN, 192, 0, stream>>>(
        aggs, aggv, Wss + l * FF * FF, Wvs + l * VV * FF, Wvv + l * VV * VV,
        Wsv + ((l + 1) < 2 ? (l + 1) * FF * VV : 0), hs, hsv, hv,
        (l + 1) < 2 ? 1 : 0);
  }
  readout_kernel<<<NN, 192, 0, stream>>>(hs, hv, Wro_s1, Wro_s2, Wro_v1,
                                         Wro_v2, out);
}

// Round 2
// 119.480 us; speedup vs baseline: 1.4927x; 1.4927x over previous
//
#include <hip/hip_runtime.h>
#include <math.h>

#define NN 768
#define FF 128
#define VV 64
#define RH 16
#define CHUNK 256

__device__ __forceinline__ float silu_f(float a) {
  return a / (1.0f + __expf(-a));
}

// ---------------------------------------------------------------------------
// init: hs[n] = embed row; hsv[n] = embed @ Wsv[0]; hv = 0
// (hsv row 0 doubles as the layer-1 constant c[v] = embed @ Wsv[0])
// ---------------------------------------------------------------------------
__global__ __launch_bounds__(192) void init_kernel(
    const float* __restrict__ embed, const float* __restrict__ Wsv0,
    float* __restrict__ hs, float* __restrict__ hsv, float* __restrict__ hv)
{
  const int n = blockIdx.x, t = threadIdx.x;
  hv[n * 192 + t] = 0.0f;
  if (t < FF) hs[n * FF + t] = embed[t];
  if (t < VV) {
    float acc = 0.f;
    #pragma unroll 8
    for (int f = 0; f < FF; ++f) acc += embed[f] * Wsv0[f * VV + t];
    hsv[n * VV + t] = acc;
  }
}

// ---------------------------------------------------------------------------
// Layer-1 edge kernel (closed form). hs == embed for every node, and
// hs_e @ Wsv == c[v] constant, so:
//   agg_s[r,f]   = embed[f]/64 * sum_h Wr2s[h,f] * R[r,h],  R[r,h]  = sum_s rf
//   agg_v[r,v,d] = c[v]/64     * sum_h Wr2v[h,v] * T[r,h,d], T[r,h,d]= sum_s rf*u_d
// One block per receiver. Phase 1: 256 senders' d/u/rf into LDS.
// Phase 2: thread t (j=t&63, q=t>>6) accumulates output j over its
// 64-sender quarter; j = h*4 + c, c==0 -> R, c==1..3 -> T[.,c-1]
// (u_s[s][3] holds 1.0 so both cases are one fma with a selected factor).
// ---------------------------------------------------------------------------
__global__ __launch_bounds__(256) void edge1_kernel(
    const float* __restrict__ x,
    const float* __restrict__ cvec,   // hsv row 0 == embed @ Wsv[0]
    const float* __restrict__ Wr1,    // [16]
    const float* __restrict__ Wr2s,   // [16][128]
    const float* __restrict__ Wr2v,   // [16][64]
    const float* __restrict__ embed,  // [128]
    float* __restrict__ agg_s,        // [N][128]
    float* __restrict__ agg_v)        // [N][64*3]
{
  __shared__ float x_s[NN * 3];
  __shared__ float rf_s[CHUNK * RH];
  __shared__ float u_s[CHUNK * 4];
  __shared__ float red[4][64];
  __shared__ float fin[64];

  const int r   = blockIdx.x;
  const int tid = threadIdx.x;
  const int j   = tid & 63;   // output index: h*4 + c
  const int q   = tid >> 6;   // sender quarter
  const int h   = j >> 2;
  const int c   = j & 3;
  const int sel = (c + 3) & 3;  // c==0 -> 3 (the 1.0 slot), else c-1

  for (int i = tid; i < NN * 3; i += 256) x_s[i] = x[i];

  float wr1[RH];
  #pragma unroll
  for (int hh = 0; hh < RH; ++hh) wr1[hh] = Wr1[hh];

  const float xr0 = x[r * 3 + 0], xr1 = x[r * 3 + 1], xr2 = x[r * 3 + 2];
  __syncthreads();

  float acc = 0.f;
  for (int cb = 0; cb < NN; cb += CHUNK) {
    // phase 1: thread tid handles sender cb+tid
    {
      const int s = cb + tid;
      const float vx = x_s[s * 3 + 0] - xr0;
      const float vy = x_s[s * 3 + 1] - xr1;
      const float vz = x_s[s * 3 + 2] - xr2;
      const float d  = sqrtf(vx * vx + vy * vy + vz * vz);
      const float iv = 1.0f / (d + 1e-8f);
      *(float4*)&u_s[tid * 4] = make_float4(vx * iv, vy * iv, vz * iv, 1.0f);
      #pragma unroll
      for (int hh = 0; hh < RH; hh += 4) {
        float4 rv;
        rv.x = silu_f(d * wr1[hh + 0]);
        rv.y = silu_f(d * wr1[hh + 1]);
        rv.z = silu_f(d * wr1[hh + 2]);
        rv.w = silu_f(d * wr1[hh + 3]);
        *(float4*)&rf_s[tid * RH + hh] = rv;
      }
    }
    __syncthreads();

    // phase 2: 64 senders in quarter q
    const int base = q * 64;
    #pragma unroll 4
    for (int si = 0; si < 64; ++si) {
      const int sl = base + si;
      acc += rf_s[sl * RH + h] * u_s[sl * 4 + sel];
    }
    __syncthreads();
  }

  red[q][j] = acc;
  __syncthreads();
  if (tid < 64) fin[tid] = red[0][tid] + red[1][tid] + red[2][tid] + red[3][tid];
  __syncthreads();

  if (tid < FF) {  // scalar output, f = tid
    float a = 0.f;
    #pragma unroll
    for (int hh = 0; hh < RH; ++hh) a += fin[hh * 4] * Wr2s[hh * FF + tid];
    agg_s[(size_t)r * FF + tid] = a * embed[tid] * (1.0f / 64.0f);
  }
  if (tid < 192) {  // vector output, v = tid/3, d = tid%3
    const int v = tid / 3, d = tid - v * 3;
    float a = 0.f;
    #pragma unroll
    for (int hh = 0; hh < RH; ++hh) a += fin[hh * 4 + 1 + d] * Wr2v[hh * VV + v];
    agg_v[(size_t)r * 192 + tid] = a * cvec[v] * (1.0f / 64.0f);
  }
}

// ---------------------------------------------------------------------------
// Layer-2 edge kernel (general hs): one block per receiver r.
//   agg_s[r,f] = (1/64) * sum_s hs[s,f]   * dot(rf[s,r], Wr2s[:,f])
//   agg_v[r,v,d]=(1/64) * sum_s hsv[s,v]  * dot(rf[s,r], Wr2v[:,v]) * u[s,r,d]
// ---------------------------------------------------------------------------
__global__ __launch_bounds__(256) void edge_kernel(
    const float* __restrict__ x,
    const float* __restrict__ hs,
    const float* __restrict__ hsv,
    const float* __restrict__ Wr1,   // [16]
    const float* __restrict__ Wr2s,  // [16][128]
    const float* __restrict__ Wr2v,  // [16][64]
    float* __restrict__ agg_s,       // [N][128]
    float* __restrict__ agg_v)       // [N][64][3]
{
  __shared__ float x_s[NN * 3];
  __shared__ float rf_s[CHUNK * RH];
  __shared__ float u_s[CHUNK * 4];

  const int r    = blockIdx.x;
  const int tid  = threadIdx.x;
  const int wid  = tid >> 6;
  const int lane = tid & 63;
  const bool is_scalar = ((wid & 1) == 0);

  for (int i = tid; i < NN * 3; i += 256) x_s[i] = x[i];

  float wr1[RH];
  #pragma unroll
  for (int h = 0; h < RH; ++h) wr1[h] = Wr1[h];

  float2 w2s[RH];
  float  w2v[RH];
  float acc0 = 0.f, acc1 = 0.f;
  float av0 = 0.f, av1 = 0.f, av2 = 0.f;
  if (is_scalar) {
    #pragma unroll
    for (int h = 0; h < RH; ++h)
      w2s[h] = *(const float2*)&Wr2s[h * FF + 2 * lane];
  } else {
    #pragma unroll
    for (int h = 0; h < RH; ++h)
      w2v[h] = Wr2v[h * VV + lane];
  }

  const float xr0 = x[r * 3 + 0], xr1 = x[r * 3 + 1], xr2 = x[r * 3 + 2];
  __syncthreads();

  for (int cb = 0; cb < NN; cb += CHUNK) {
    {
      const int s = cb + tid;
      const float vx = x_s[s * 3 + 0] - xr0;
      const float vy = x_s[s * 3 + 1] - xr1;
      const float vz = x_s[s * 3 + 2] - xr2;
      const float d  = sqrtf(vx * vx + vy * vy + vz * vz);
      const float iv = 1.0f / (d + 1e-8f);
      *(float4*)&u_s[tid * 4] = make_float4(vx * iv, vy * iv, vz * iv, 0.f);
      #pragma unroll
      for (int h = 0; h < RH; h += 4) {
        float4 rv;
        rv.x = silu_f(d * wr1[h + 0]);
        rv.y = silu_f(d * wr1[h + 1]);
        rv.z = silu_f(d * wr1[h + 2]);
        rv.w = silu_f(d * wr1[h + 3]);
        *(float4*)&rf_s[tid * RH + h] = rv;
      }
    }
    __syncthreads();

    const int base = (wid >> 1) * 128;
    if (is_scalar) {
      const float* hsp = hs + (size_t)cb * FF + 2 * lane;
      #pragma unroll 2
      for (int si = 0; si < 128; ++si) {
        const int sl = base + si;
        const float4* rp = (const float4*)&rf_s[sl * RH];
        float qv[RH];
        *(float4*)&qv[0]  = rp[0];
        *(float4*)&qv[4]  = rp[1];
        *(float4*)&qv[8]  = rp[2];
        *(float4*)&qv[12] = rp[3];
        const float2 h2 = *(const float2*)&hsp[(size_t)sl * FF];
        float ws0 = 0.f, ws1 = 0.f;
        #pragma unroll
        for (int h = 0; h < RH; ++h) {
          ws0 += qv[h] * w2s[h].x;
          ws1 += qv[h] * w2s[h].y;
        }
        acc0 += h2.x * ws0;
        acc1 += h2.y * ws1;
      }
    } else {
      const float* hvp = hsv + (size_t)cb * VV + lane;
      #pragma unroll 2
      for (int si = 0; si < 128; ++si) {
        const int sl = base + si;
        const float4* rp = (const float4*)&rf_s[sl * RH];
        float qv[RH];
        *(float4*)&qv[0]  = rp[0];
        *(float4*)&qv[4]  = rp[1];
        *(float4*)&qv[8]  = rp[2];
        *(float4*)&qv[12] = rp[3];
        const float hm = hvp[(size_t)sl * VV];
        float wv = 0.f;
        #pragma unroll
        for (int h = 0; h < RH; ++h) wv += qv[h] * w2v[h];
        const float m = hm * wv;
        const float4 u = *(const float4*)&u_s[sl * 4];
        av0 += m * u.x;
        av1 += m * u.y;
        av2 += m * u.z;
      }
    }
    __syncthreads();
  }

  if (wid == 2) { rf_s[lane * 2] = acc0; rf_s[lane * 2 + 1] = acc1; }
  if (wid == 3) {
    rf_s[256 + lane * 3 + 0] = av0;
    rf_s[256 + lane * 3 + 1] = av1;
    rf_s[256 + lane * 3 + 2] = av2;
  }
  __syncthreads();
  if (wid == 0) {
    const float o0 = (acc0 + rf_s[lane * 2])     * (1.0f / 64.0f);
    const float o1 = (acc1 + rf_s[lane * 2 + 1]) * (1.0f / 64.0f);
    *(float2*)&agg_s[(size_t)r * FF + 2 * lane] = make_float2(o0, o1);
  }
  if (wid == 1) {
    agg_v[r * 192 + lane * 3 + 0] = (av0 + rf_s[256 + lane * 3 + 0]) * (1.0f / 64.0f);
    agg_v[r * 192 + lane * 3 + 1] = (av1 + rf_s[256 + lane * 3 + 1]) * (1.0f / 64.0f);
    agg_v[r * 192 + lane * 3 + 2] = (av2 + rf_s[256 + lane * 3 + 2]) * (1.0f / 64.0f);
  }
}

// ---------------------------------------------------------------------------
// node update: hs = silu(hs + agg_s@Wss + inv@Wvs); hv += agg_v@Wvv;
//              hsv = hs_new @ Wsv_next (for next layer)
// ---------------------------------------------------------------------------
__global__ __launch_bounds__(192) void node_kernel(
    const float* __restrict__ agg_s,
    const float* __restrict__ agg_v,
    const float* __restrict__ Wss,
    const float* __restrict__ Wvs,
    const float* __restrict__ Wvv,
    const float* __restrict__ Wsv_next,
    float* __restrict__ hs,
    float* __restrict__ hsv,
    float* __restrict__ hv,
    int has_next)
{
  __shared__ float as_l[FF];
  __shared__ float av_l[192];
  __shared__ float inv_l[VV];
  __shared__ float hsn[FF];
  const int n = blockIdx.x, t = threadIdx.x;
  if (t < FF) as_l[t] = agg_s[n * FF + t];
  av_l[t] = agg_v[n * 192 + t];
  __syncthreads();
  if (t < VV) {
    const float a0 = av_l[t * 3 + 0], a1 = av_l[t * 3 + 1], a2 = av_l[t * 3 + 2];
    inv_l[t] = a0 * a0 + a1 * a1 + a2 * a2;
  }
  __syncthreads();
  if (t < FF) {
    float acc = hs[n * FF + t];
    #pragma unroll 4
    for (int k = 0; k < FF; ++k) acc += as_l[k] * Wss[k * FF + t];
    #pragma unroll 4
    for (int v = 0; v < VV; ++v) acc += inv_l[v] * Wvs[v * FF + t];
    const float hnew = silu_f(acc);
    hs[n * FF + t] = hnew;
    hsn[t] = hnew;
  }
  {
    const int w = t / 3, d = t - w * 3;
    float acc = hv[n * 192 + t];
    #pragma unroll 4
    for (int v = 0; v < VV; ++v) acc += av_l[v * 3 + d] * Wvv[v * VV + w];
    hv[n * 192 + t] = acc;
  }
  __syncthreads();
  if (has_next && t < VV) {
    float acc = 0.f;
    #pragma unroll 4
    for (int f = 0; f < FF; ++f) acc += hsn[f] * Wsv_next[f * VV + t];
    hsv[n * VV + t] = acc;
  }
}

// ---------------------------------------------------------------------------
// readout
// ---------------------------------------------------------------------------
__global__ __launch_bounds__(192) void readout_kernel(
    const float* __restrict__ hs,
    const float* __restrict__ hv,
    const float* __restrict__ Wro_s1,
    const float* __restrict__ Wro_s2,
    const float* __restrict__ Wro_v1,
    const float* __restrict__ Wro_v2,
    float* __restrict__ out)
{
  __shared__ float hs_l[FF];
  __shared__ float hv_l[192];
  __shared__ float t1[FF];
  __shared__ float tv1[192];
  const int n = blockIdx.x, t = threadIdx.x;
  if (t < FF) hs_l[t] = hs[n * FF + t];
  hv_l[t] = hv[n * 192 + t];
  __syncthreads();
  if (t < FF) {
    float acc = 0.f;
    #pragma unroll 4
    for (int k = 0; k < FF; ++k) acc += hs_l[k] * Wro_s1[k * FF + t];
    t1[t] = silu_f(acc);
  }
  {
    const int w = t / 3, d = t - w * 3;
    float acc = 0.f;
    #pragma unroll 4
    for (int v = 0; v < VV; ++v) acc += hv_l[v * 3 + d] * Wro_v1[v * VV + w];
    tv1[t] = acc;
  }
  __syncthreads();
  if (t < 64) {
    float acc = 0.f;
    #pragma unroll 4
    for (int f = 0; f < FF; ++f) acc += t1[f] * Wro_s2[f * 64 + t];
    out[n * 160 + t] = acc;
  }
  if (t >= 64 && t < 160) {
    const int j = t - 64;
    const int w2 = j / 3, d = j - w2 * 3;
    float acc = 0.f;
    #pragma unroll 4
    for (int w = 0; w < VV; ++w) acc += tv1[w * 3 + d] * Wro_v2[w * 32 + w2];
    out[n * 160 + 64 + j] = acc;
  }
}

// ---------------------------------------------------------------------------
extern "C" void kernel_launch(void* const* d_in, const int* in_sizes, int n_in,
                              void* d_out, int out_size, void* d_ws, size_t ws_size,
                              hipStream_t stream) {
  const float* x      = (const float*)d_in[0];
  const float* embed  = (const float*)d_in[3];
  const float* Wr1    = (const float*)d_in[4];   // [2][1][16]
  const float* Wr2s   = (const float*)d_in[5];   // [2][16][128]
  const float* Wr2v   = (const float*)d_in[6];   // [2][16][64]
  const float* Wsv    = (const float*)d_in[7];   // [2][128][64]
  const float* Wss    = (const float*)d_in[8];   // [2][128][128]
  const float* Wvs    = (const float*)d_in[9];   // [2][64][128]
  const float* Wvv    = (const float*)d_in[10];  // [2][64][64]
  const float* Wro_s1 = (const float*)d_in[11];
  const float* Wro_s2 = (const float*)d_in[12];
  const float* Wro_v1 = (const float*)d_in[13];
  const float* Wro_v2 = (const float*)d_in[14];

  float* ws_f = (float*)d_ws;
  float* hs   = ws_f;                 // [768][128]
  float* hsv  = hs   + NN * FF;       // [768][64]
  float* hv   = hsv  + NN * VV;       // [768][192]
  float* aggs = hv   + NN * 192;      // [768][128]
  float* aggv = aggs + NN * FF;       // [768][192]
  float* out  = (float*)d_out;

  init_kernel<<<NN, 192, 0, stream>>>(embed, Wsv, hs, hsv, hv);

  // ---- layer 0: closed-form edge pass (hs == embed everywhere) ----
  edge1_kernel<<<NN, 256, 0, stream>>>(x, hsv /* row 0 = c[v] */, Wr1, Wr2s,
                                       Wr2v, embed, aggs, aggv);
  node_kernel<<<NN, 192, 0, stream>>>(
      aggs, aggv, Wss, Wvs, Wvv, Wsv + FF * VV, hs, hsv, hv, 1);

  // ---- layer 1: general edge pass ----
  edge_kernel<<<NN, 256, 0, stream>>>(
      x, hs, hsv, Wr1 + RH, Wr2s + RH * FF, Wr2v + RH * VV, aggs, aggv);
  node_kernel<<<NN, 192, 0, stream>>>(
      aggs, aggv, Wss + FF * FF, Wvs + VV * FF, Wvv + VV * VV, Wsv, hs, hsv,
      hv, 0);

  readout_kernel<<<NN, 192, 0, stream>>>(hs, hv, Wro_s1, Wro_s2, Wro_v1,
                                         Wro_v2, out);
}